// Round 2
// baseline (205.492 us; speedup 1.0000x reference)
//
#include <hip/hip_runtime.h>

// Problem dims (fixed by reference)
#define T_TOTAL (32 * 4096)   // B*S = 131072 tokens
#define FDIM 256
#define NG 2                  // groups
#define NN 128                // entries per group
#define DDIM 128              // group dim
#define EDIM 256              // embed dim

#define TAU 0.004f            // bf16x2-vs-f32 safety margin for argmax gap
#define CAP 16384             // max flagged (t,g) entries (expected ~1k)

typedef __attribute__((ext_vector_type(4))) float f32x4;
typedef __attribute__((ext_vector_type(8))) short short8;

// ---------------------------------------------------------------------------
// Kernel A: CO[g][n][e] = sum_d codebooks[g][n][d] * W_out[g*128+d][e]
// ---------------------------------------------------------------------------
__global__ __launch_bounds__(256) void co_kernel(
    const float* __restrict__ codebooks,  // [2][128][128]
    const float* __restrict__ W_out,      // [256][256]
    float* __restrict__ CO)               // [2][128][256]
{
    const int gn = blockIdx.x;            // 0..255 ; g = gn>>7
    const int g  = gn >> 7;
    __shared__ float cb[DDIM];
    const int tid = threadIdx.x;
    if (tid < DDIM) cb[tid] = codebooks[gn * DDIM + tid];
    __syncthreads();
    float acc = 0.f;
    const float* wcol = W_out + (g * DDIM) * EDIM + tid;
#pragma unroll 4
    for (int d = 0; d < DDIM; ++d) acc += cb[d] * wcol[d * EDIM];
    CO[gn * EDIM + tid] = acc;
}

// ---------------------------------------------------------------------------
// Kernel W: split W_logits into two truncated-bf16 levels, TRANSPOSED to
// BT[lev][g][n][k] so MFMA B-frag loads are 16B-contiguous. Also zeroes the
// flag counter (runs before the logits kernel every launch).
// ---------------------------------------------------------------------------
__global__ __launch_bounds__(128) void wsplit_kernel(
    const float* __restrict__ Wl,   // [2][128 k][128 n]
    short* __restrict__ BT,         // [2 lev][2 g][128 n][128 k] bf16 bits
    int* __restrict__ flag_count)
{
    const int b = blockIdx.x;       // g*128 + n
    const int g = b >> 7, n = b & 127;
    const int k = threadIdx.x;
    const float x = Wl[((size_t)g * DDIM + k) * NN + n];
    const unsigned u = __float_as_uint(x);
    const float hi = __uint_as_float(u & 0xffff0000u);
    const float r = x - hi;                       // exact
    const unsigned u2 = __float_as_uint(r);
    BT[(size_t)g * 16384 + n * 128 + k] = (short)(u >> 16);
    BT[(size_t)32768 + g * 16384 + n * 128 + k] = (short)(u2 >> 16);
    if (b == 0 && k == 0) *flag_count = 0;
}

// ---------------------------------------------------------------------------
// Kernel B: bf16x2 MFMA logits + gumbel argmax with top-2 gap flagging.
// Block: 256 threads = 4 waves. Wave w: group g=w&1, token half mh=w>>1.
// Wave computes 32 tokens x 128 n via 2 Mtiles x 8 Ntiles of 16x16x32 MFMA.
// ---------------------------------------------------------------------------
__global__ __launch_bounds__(256) void logits_mfma_kernel(
    const float* __restrict__ features,   // [T][256]
    const float* __restrict__ gumbel,     // [T][2][128]
    const short* __restrict__ BT,         // [2][2][128][128] bf16 bits
    const float* __restrict__ bl,         // [2][128]
    float* __restrict__ idx_f,            // [T][2] float-encoded indices
    int* __restrict__ flag_count,
    int* __restrict__ flag_list)
{
    const int tid = threadIdx.x;
    const int w  = tid >> 6;      // wave 0..3
    const int g  = w & 1;
    const int mh = w >> 1;
    const int l  = tid & 63;
    const int q  = l & 15;        // fragment row/col index
    const int h  = l >> 4;        // k-chunk selector
    const int t0 = blockIdx.x * 64 + mh * 32;

    const f32x4 zero = {0.f, 0.f, 0.f, 0.f};
    f32x4 acc[2][8];
#pragma unroll
    for (int mt = 0; mt < 2; ++mt)
#pragma unroll
        for (int nt = 0; nt < 8; ++nt) acc[mt][nt] = zero;

    for (int ks = 0; ks < 4; ++ks) {
        // ---- A fragments: load 8 consecutive f32 per lane per Mtile, split
        short8 A1[2], A2[2];
#pragma unroll
        for (int mt = 0; mt < 2; ++mt) {
            const float* ap = features + (size_t)(t0 + mt * 16 + q) * FDIM
                              + g * DDIM + ks * 32 + h * 8;
            const float4 v0 = *reinterpret_cast<const float4*>(ap);
            const float4 v1 = *reinterpret_cast<const float4*>(ap + 4);
            const float xs[8] = {v0.x, v0.y, v0.z, v0.w, v1.x, v1.y, v1.z, v1.w};
#pragma unroll
            for (int j = 0; j < 8; ++j) {
                const unsigned u = __float_as_uint(xs[j]);
                const float hi = __uint_as_float(u & 0xffff0000u);
                const float r = xs[j] - hi;           // exact
                const unsigned u2 = __float_as_uint(r);
                A1[mt][j] = (short)(u >> 16);
                A2[mt][j] = (short)(u2 >> 16);
            }
        }
        // ---- B fragments from L2-resident pre-split W^T, 3 MFMAs per tile
#pragma unroll
        for (int nt = 0; nt < 8; ++nt) {
            const short* bp = BT + (size_t)g * 16384 + (nt * 16 + q) * 128
                              + ks * 32 + h * 8;
            const short8 B1 = *reinterpret_cast<const short8*>(bp);
            const short8 B2 = *reinterpret_cast<const short8*>(bp + 32768);
#pragma unroll
            for (int mt = 0; mt < 2; ++mt) {
                acc[mt][nt] = __builtin_amdgcn_mfma_f32_16x16x32_bf16(A1[mt], B1, acc[mt][nt], 0, 0, 0);
                acc[mt][nt] = __builtin_amdgcn_mfma_f32_16x16x32_bf16(A2[mt], B1, acc[mt][nt], 0, 0, 0);
                acc[mt][nt] = __builtin_amdgcn_mfma_f32_16x16x32_bf16(A1[mt], B2, acc[mt][nt], 0, 0, 0);
            }
        }
    }

    // ---- epilogue: +bias +gumbel, top-2 argmax per token, flag near-ties
    float blv[8];
#pragma unroll
    for (int nt = 0; nt < 8; ++nt) blv[nt] = bl[g * NN + nt * 16 + q];

#pragma unroll
    for (int mt = 0; mt < 2; ++mt) {
#pragma unroll
        for (int r = 0; r < 4; ++r) {
            const int t = t0 + mt * 16 + h * 4 + r;   // D row = (lane>>4)*4+reg
            const float* gp = gumbel + ((size_t)t * NG + g) * NN;
            float m1, m2;
            int i1;
            {
                const float v = acc[mt][0][r] + blv[0] + gp[q];
                m1 = v; i1 = q; m2 = -3.4e38f;
            }
#pragma unroll
            for (int nt = 1; nt < 8; ++nt) {
                const float v = acc[mt][nt][r] + blv[nt] + gp[nt * 16 + q];
                if (v > m1) { m2 = m1; m1 = v; i1 = nt * 16 + q; }
                else        { m2 = fmaxf(m2, v); }
            }
            // reduce across the 16 lanes sharing this token (same h group)
#pragma unroll
            for (int off = 1; off < 16; off <<= 1) {
                const float om1 = __shfl_xor(m1, off);
                const int   oi1 = __shfl_xor(i1, off);
                const float om2 = __shfl_xor(m2, off);
                if (om1 > m1)      { m2 = fmaxf(m1, om2); m1 = om1; i1 = oi1; }
                else if (om1 < m1) { m2 = fmaxf(m2, om1); }
                else               { m2 = m1; i1 = min(i1, oi1); }
            }
            if (q == 0) {
                idx_f[(size_t)t * NG + g] = (float)i1;
                if (m1 - m2 < TAU) {
                    const int p = atomicAdd(flag_count, 1);
                    if (p < CAP) flag_list[p] = t * NG + g;
                }
            }
        }
    }
}

// ---------------------------------------------------------------------------
// Kernel F: exact sequential-f32 recompute for flagged (t,g) — bitwise
// reproduces the round-1 kernel's fmaf chain (k = 0..127 ascending),
// which matched the numpy reference exactly.
// ---------------------------------------------------------------------------
__global__ __launch_bounds__(128) void fixup_kernel(
    const float* __restrict__ features,
    const float* __restrict__ gumbel,
    const float* __restrict__ Wl,         // [2][128 k][128 n]
    const float* __restrict__ bl,
    float* __restrict__ idx_f,
    const int* __restrict__ flag_count,
    const int* __restrict__ flag_list)
{
    __shared__ float sm[2];
    __shared__ int   si[2];
    int total = *flag_count;
    if (total > CAP) total = CAP;
    const int n = threadIdx.x;

    for (int e = blockIdx.x; e < total; e += gridDim.x) {
        const int code = flag_list[e];
        const int t = code >> 1, g = code & 1;
        const float* fp = features + (size_t)t * FDIM + g * DDIM;
        const float* wp = Wl + (size_t)g * DDIM * NN + n;
        float dot = 0.f;
        for (int k = 0; k < DDIM; ++k) dot = fmaf(fp[k], wp[(size_t)k * NN], dot);
        const float v = (dot + bl[g * NN + n]) + gumbel[((size_t)t * NG + g) * NN + n];

        float m = v; int bi = n;
#pragma unroll
        for (int off = 1; off < 64; off <<= 1) {
            const float om = __shfl_xor(m, off);
            const int   ob = __shfl_xor(bi, off);
            if (om > m || (om == m && ob < bi)) { m = om; bi = ob; }
        }
        if ((n & 63) == 0) { sm[n >> 6] = m; si[n >> 6] = bi; }
        __syncthreads();
        if (n == 0) {
            const float mA = sm[0], mB = sm[1];
            const int bA = si[0], bB = si[1];
            const int best = (mB > mA || (mB == mA && bB < bA)) ? bB : bA;
            idx_f[code] = (float)best;
        }
        __syncthreads();
    }
}

// ---------------------------------------------------------------------------
// Kernel C: out[t][e] = CO[0][i0][e] + CO[1][i1][e] + b_out[e]
// ---------------------------------------------------------------------------
__global__ __launch_bounds__(256) void out_kernel(
    const float* __restrict__ CO,      // [2][128][256]
    const float* __restrict__ b_out,   // [256]
    const float* __restrict__ idx_f,   // [T][2] float-encoded
    float* __restrict__ out)           // [T][256]
{
    const int tid = threadIdx.x;
    const int e4  = tid & 63;    // float4 index in e
    const int ts  = tid >> 6;    // 0..3
    const int tbase = blockIdx.x * 16;
    const float4 b = *reinterpret_cast<const float4*>(b_out + e4 * 4);

#pragma unroll
    for (int it = 0; it < 4; ++it) {
        const int t  = tbase + it * 4 + ts;
        const int i0 = (int)idx_f[t * NG + 0];
        const int i1 = (int)idx_f[t * NG + 1];
        const float4 c0 = *reinterpret_cast<const float4*>(CO + (size_t)i0 * EDIM + e4 * 4);
        const float4 c1 = *reinterpret_cast<const float4*>(CO + (size_t)(NN + i1) * EDIM + e4 * 4);
        float4 o;
        o.x = c0.x + c1.x + b.x;
        o.y = c0.y + c1.y + b.y;
        o.z = c0.z + c1.z + b.z;
        o.w = c0.w + c1.w + b.w;
        *reinterpret_cast<float4*>(out + (size_t)t * EDIM + e4 * 4) = o;
    }
}

// ---------------------------------------------------------------------------
extern "C" void kernel_launch(void* const* d_in, const int* in_sizes, int n_in,
                              void* d_out, int out_size, void* d_ws, size_t ws_size,
                              hipStream_t stream) {
    const float* features  = (const float*)d_in[0];  // [32,4096,256]
    const float* gumbel    = (const float*)d_in[1];  // [32,4096,2,128]
    const float* Wl        = (const float*)d_in[2];  // [2,128,128]
    const float* bl        = (const float*)d_in[3];  // [2,128]
    const float* codebooks = (const float*)d_in[4];  // [2,128,128]
    const float* W_out     = (const float*)d_in[5];  // [256,256]
    const float* b_out     = (const float*)d_in[6];  // [256]

    float* out   = (float*)d_out;                    // [T,256]
    float* idx_f = out + (size_t)T_TOTAL * EDIM;     // [T,2] float-encoded indices

    // ws layout: CO (256KB) | BT (128KB) | flag_count (pad 256B) | flag_list (64KB)
    char* ws = (char*)d_ws;
    float* CO         = (float*)ws;                        // 262144 B
    short* BT         = (short*)(ws + 262144);             // 131072 B
    int*   flag_count = (int*)(ws + 262144 + 131072);      // @393216
    int*   flag_list  = (int*)(ws + 393216 + 256);         // @393472, 64KB

    wsplit_kernel<<<NG * NN, 128, 0, stream>>>(Wl, BT, flag_count);
    co_kernel<<<NG * NN, 256, 0, stream>>>(codebooks, W_out, CO);
    logits_mfma_kernel<<<T_TOTAL / 64, 256, 0, stream>>>(
        features, gumbel, BT, bl, idx_f, flag_count, flag_list);
    fixup_kernel<<<128, 128, 0, stream>>>(
        features, gumbel, Wl, bl, idx_f, flag_count, flag_list);
    out_kernel<<<T_TOTAL / 16, 256, 0, stream>>>(CO, b_out, idx_f, out);
}